// Round 10
// baseline (97.392 us; speedup 1.0000x reference)
//
#include <hip/hip_runtime.h>
#include <array>

// Problem constants (fixed by reference setup_inputs)
constexpr int Cc   = 3;
constexpr int Hc   = 160;
constexpr int Wc   = 160;
constexpr int Hoc  = 158;
constexpr int Woc  = 158;
constexpr int Lc   = Hoc * Woc;    // 24964
constexpr int Ntot = 4 * Lc;       // 99856
constexpr int Nhalf= Ntot / 2;     // 49928 (Ntot even)
constexpr int NCH  = 8;
constexpr int MDd  = 54;           // 2 * C * 3 * 3

// ---------------------------------------------------------------------------
// Batcher odd-even mergesort network for n=64, pruned to wires < 54 (monotone
// network; pruned wires are implicit -inf pads under the descending
// comparator). Same structure proven correct in rounds 0-4/6/7/8/9.
// ---------------------------------------------------------------------------
struct CEpair { unsigned char lo, hi; };

constexpr int count_ces() {
    int cnt = 0;
    for (int p = 1; p < 64; p <<= 1)
        for (int k = p; k >= 1; k >>= 1)
            for (int j = k % p; j + k < 64; j += 2 * k)
                for (int i = 0; i < k; ++i) {
                    const int lo = i + j, hi = i + j + k;
                    if (hi < MDd && (lo / (2 * p) == hi / (2 * p))) ++cnt;
                }
    return cnt;
}
constexpr int NCE = count_ces();

constexpr std::array<CEpair, NCE> make_net() {
    std::array<CEpair, NCE> a{};
    int cnt = 0;
    for (int p = 1; p < 64; p <<= 1)
        for (int k = p; k >= 1; k >>= 1)
            for (int j = k % p; j + k < 64; j += 2 * k)
                for (int i = 0; i < k; ++i) {
                    const int lo = i + j, hi = i + j + k;
                    if (hi < MDd && (lo / (2 * p) == hi / (2 * p))) {
                        a[cnt].lo = (unsigned char)lo;
                        a[cnt].hi = (unsigned char)hi;
                        ++cnt;
                    }
                }
    return a;
}
constexpr auto NET = make_net();

// F64-PACKED compare-exchange (rounds 7/9, verified absmax 0.0): each sort
// element is ONE double whose bit pattern is
// (f32 key bits << 32) | (f32 weight bits).
// Monotone embedding: for distinct f32 keys, f64-compare equals the f32 value
// compare (both sign-magnitude orders; f32 Inf widens to a huge FINITE f64;
// f64 NaN impossible from finite x+mask sums). Exact-key ties are broken by
// weight bits; tied keys carry equal values so the selected OUTPUT is
// unaffected. CE = v_max_f64 + v_min_f64 (4-cyc half-rate ops — 8-cyc ruled
// out: measured 35.8us beats the 8-cyc full-issue floor of 40.7us).
// Kept as inline asm: round 2 measured plain-C CEs spilling to scratch (22x).
__device__ __forceinline__ void ce(double &a, double &b) {
    double hi, lo;
    asm("v_max_f64 %0, %2, %3\n\t"
        "v_min_f64 %1, %2, %3"
        : "=&v"(hi), "=v"(lo)
        : "v"(a), "v"(b));
    a = hi; b = lo;
}

// Fence every 8 interleaved CE pairs (16 CEs): scratch-spill guard, verified
// in rounds 4/6/7/9.
constexpr int FENCE_EVERY = 8;

// ROUND-10 EXPERIMENT: 2 pixels per thread (streams A/B), every CE/cumsum op
// interleaved A/B -> adjacent instructions are always independent, covering
// the f64 dep chains that left ~27% of issue slots idle at 3 waves/SIMD
// (measured 35.8us vs the 26.4us 100%-issue floor). State 2x108 + temps ~240
// regs -> (256,2): 256-reg budget, 2 waves/SIMD = 4 independent streams/SIMD.
// TRIPWIRE: WRITE_SIZE >> 6.24 MB = spill -> revert to round-9 and declare.
__global__ __launch_bounds__(256, 2) void wos_kernel(
    const float* __restrict__ x, const float* __restrict__ weight,
    const float* __restrict__ bias, const float* __restrict__ mask,
    float* __restrict__ out)
{
    const int lane = threadIdx.x & 63;
    const int wave = threadIdx.x >> 6;
    const int grp  = blockIdx.x >> 1;
    // nc is wave-uniform: assert it so weight/mask/bias reads become scalar loads.
    const int nc   = __builtin_amdgcn_readfirstlane(((blockIdx.x & 1) << 2) | wave);
    const int nA   = grp * 64 + lane;
    if (nA >= Nhalf) return;            // no cross-lane ops: early exit safe
    const int nB   = nA + Nhalf;        // nB < Ntot iff nA < Nhalf

    // Per-stream pixel coordinates.
    const int bA  = nA / Lc,  lA = nA - bA * Lc;
    const int hoA = lA / Woc, woA = lA - hoA * Woc;
    const int bB  = nB / Lc,  lB = nB - bB * Lc;
    const int hoB = lB / Woc, woB = lB - hoB * Woc;

    const float* xbA = x + (bA * Cc) * (Hc * Wc);
    const float* xbB = x + (bB * Cc) * (Hc * Wc);
    const float* mk = mask + nc * MDd;      // wave-uniform -> scalar loads
    const float* wr = weight + nc * MDd;    // wave-uniform -> scalar loads
    const float  bi = bias[nc];             // shared by both streams

    // Build packed elements for both streams (high = key bits, low = weight
    // bits; mk[27+d] - v == (-v) + mk[27+d] bit-exactly). Interleaved A/B.
    double keyA[MDd], keyB[MDd];
    #pragma unroll
    for (int c = 0; c < 3; ++c) {
        #pragma unroll
        for (int r = 0; r < 3; ++r) {
            #pragma unroll
            for (int s = 0; s < 3; ++s) {
                const int d = c * 9 + r * 3 + s;
                const unsigned wlo = __float_as_uint(wr[d]);
                const unsigned whi = __float_as_uint(wr[27 + d]);
                const float vA = xbA[(c * Hc + hoA + r) * Wc + woA + s];
                const float vB = xbB[(c * Hc + hoB + r) * Wc + woB + s];
                keyA[d] = __longlong_as_double((long long)(
                    ((unsigned long long)__float_as_uint(vA + mk[d]) << 32) | wlo));
                keyB[d] = __longlong_as_double((long long)(
                    ((unsigned long long)__float_as_uint(vB + mk[d]) << 32) | wlo));
                keyA[27 + d] = __longlong_as_double((long long)(
                    ((unsigned long long)__float_as_uint(mk[27 + d] - vA) << 32) | whi));
                keyB[27 + d] = __longlong_as_double((long long)(
                    ((unsigned long long)__float_as_uint(mk[27 + d] - vB) << 32) | whi));
            }
        }
    }
    __builtin_amdgcn_sched_barrier(0);   // build may not bleed into the sort

    // Flattened sorting network, A/B interleaved: every adjacent instruction
    // pair is independent -> per-wave ILP covers the f64 latency.
    #pragma unroll
    for (int ci = 0; ci < NCE; ++ci) {
        ce(keyA[NET[ci].lo], keyA[NET[ci].hi]);
        ce(keyB[NET[ci].lo], keyB[NET[ci].hi]);
        if (ci % FENCE_EVERY == FENCE_EVERY - 1)
            __builtin_amdgcn_sched_barrier(0);
    }
    __builtin_amdgcn_sched_barrier(0);   // sort may not bleed into the cumsum

    // Sequential fp32 cumsum of the (exact, raw-bits) weights in sorted
    // descending-key order — bit-matches the reference summation. Two
    // independent chains, interleaved.
    const unsigned long long uA0 = (unsigned long long)__double_as_longlong(keyA[0]);
    const unsigned long long uB0 = (unsigned long long)__double_as_longlong(keyB[0]);
    float accA = 0.0f, accB = 0.0f;
    float selA = __uint_as_float((unsigned)(uA0 >> 32));
    float selB = __uint_as_float((unsigned)(uB0 >> 32));
    #pragma unroll
    for (int r = 0; r < MDd; ++r) {
        const unsigned long long uA = (unsigned long long)__double_as_longlong(keyA[r]);
        const unsigned long long uB = (unsigned long long)__double_as_longlong(keyB[r]);
        accA += __uint_as_float((unsigned)uA);           // low word: weight
        accB += __uint_as_float((unsigned)uB);
        const float kvA = __uint_as_float((unsigned)(uA >> 32)); // high: key
        const float kvB = __uint_as_float((unsigned)(uB >> 32));
        selA = (accA <= bi) ? kvA : selA;
        selB = (accB <= bi) ? kvB : selB;
    }

    out[nA * NCH + nc] = selA;
    out[nB * NCH + nc] = selB;
}

extern "C" void kernel_launch(void* const* d_in, const int* in_sizes, int n_in,
                              void* d_out, int out_size, void* d_ws, size_t ws_size,
                              hipStream_t stream) {
    const float* x      = (const float*)d_in[0];
    const float* weight = (const float*)d_in[1];
    const float* bias   = (const float*)d_in[2];
    const float* mask   = (const float*)d_in[3];
    float* out = (float*)d_out;

    const int ngrp = (Nhalf + 63) / 64;     // 781
    dim3 grid(ngrp * 2);                    // x2 blocks: 8 nc / 4 waves
    wos_kernel<<<grid, 256, 0, stream>>>(x, weight, bias, mask, out);
}

// Round 11
// 86.439 us; speedup vs baseline: 1.1267x; 1.1267x over previous
//
#include <hip/hip_runtime.h>
#include <array>

// Problem constants (fixed by reference setup_inputs)
constexpr int Cc   = 3;
constexpr int Hc   = 160;
constexpr int Wc   = 160;
constexpr int Hoc  = 158;
constexpr int Woc  = 158;
constexpr int Lc   = Hoc * Woc;    // 24964
constexpr int Ntot = 4 * Lc;       // 99856
constexpr int NCH  = 8;
constexpr int MDd  = 54;           // 2 * C * 3 * 3

// ---------------------------------------------------------------------------
// Batcher odd-even mergesort network for n=64, pruned to wires < 54 (monotone
// network; pruned wires are implicit -inf pads under the descending
// comparator). Same structure proven correct in rounds 0-4/6/7/8/9.
// ---------------------------------------------------------------------------
struct CEpair { unsigned char lo, hi; };

constexpr int count_ces() {
    int cnt = 0;
    for (int p = 1; p < 64; p <<= 1)
        for (int k = p; k >= 1; k >>= 1)
            for (int j = k % p; j + k < 64; j += 2 * k)
                for (int i = 0; i < k; ++i) {
                    const int lo = i + j, hi = i + j + k;
                    if (hi < MDd && (lo / (2 * p) == hi / (2 * p))) ++cnt;
                }
    return cnt;
}
constexpr int NCE = count_ces();

constexpr std::array<CEpair, NCE> make_net() {
    std::array<CEpair, NCE> a{};
    int cnt = 0;
    for (int p = 1; p < 64; p <<= 1)
        for (int k = p; k >= 1; k >>= 1)
            for (int j = k % p; j + k < 64; j += 2 * k)
                for (int i = 0; i < k; ++i) {
                    const int lo = i + j, hi = i + j + k;
                    if (hi < MDd && (lo / (2 * p) == hi / (2 * p))) {
                        a[cnt].lo = (unsigned char)lo;
                        a[cnt].hi = (unsigned char)hi;
                        ++cnt;
                    }
                }
    return a;
}
constexpr auto NET = make_net();

// F64-PACKED compare-exchange (rounds 7/9, verified absmax 0.0, ~36 us):
// each sort element is ONE double whose bit pattern is
// (f32 key bits << 32) | (f32 weight bits).
//
// Monotone embedding: for distinct f32 keys a,b, f64-compare of (a<<32|x) vs
// (b<<32|y) equals the f32 value compare (both sign-magnitude orders; f32 Inf
// widens to a huge FINITE f64; f64 NaN would require an f32 NaN key,
// impossible from finite x+mask sums). Exact-key ties are broken by weight
// bits; tied keys carry equal values so the selected OUTPUT is unaffected.
//
// CE = v_max_f64 + v_min_f64: 2 instructions, no vcc, payload rides free.
// Kept as inline asm: round 2 measured plain-C CEs spilling to scratch (22x).
//
// SETTLED EXPERIMENT LEDGER (do not retry):
//  - launch_bounds (256,4) + per-c fences: neutral-negative (round 8).
//  - 2 pixels/thread ILP at (256,2): 216-double state -> allocator caps arch
//    at 128, spills ~5 MB to scratch, occupancy 12%, kernel 47us (round 10).
//  - payload-free bit-steal sort: correctness-fatal, absmax 0.234 (round 5).
//  - plain-C CE: scratch catastrophe (round 2) or shuttle-parity (round 6).
__device__ __forceinline__ void ce(double &a, double &b) {
    double hi, lo;
    asm("v_max_f64 %0, %2, %3\n\t"
        "v_min_f64 %1, %2, %3"
        : "=&v"(hi), "=v"(lo)
        : "v"(a), "v"(b));
    a = hi; b = lo;
}

// Fences: scratch-spill guard (bounds scheduler live-range inflation);
// verified effective in rounds 4/6/7/9.
constexpr int FENCE_EVERY = 16;

// (256,3): the measured-best config (rounds 7/9: 86.6-86.8 us harness,
// ~35.8 us kernel, 73% of the 100%-issue floor; both occupancy directions
// and 2-stream ILP measured as regressions).
__global__ __launch_bounds__(256, 3) void wos_kernel(
    const float* __restrict__ x, const float* __restrict__ weight,
    const float* __restrict__ bias, const float* __restrict__ mask,
    float* __restrict__ out)
{
    const int lane = threadIdx.x & 63;
    const int wave = threadIdx.x >> 6;
    const int grp  = blockIdx.x >> 1;
    // nc is wave-uniform: assert it so weight/mask/bias reads become scalar loads.
    const int nc   = __builtin_amdgcn_readfirstlane(((blockIdx.x & 1) << 2) | wave);
    const int n    = grp * 64 + lane;
    if (n >= Ntot) return;

    const int b  = n / Lc;
    const int l  = n - b * Lc;
    const int ho = l / Woc;
    const int wo = l - ho * Woc;

    const float* xb = x + (b * Cc) * (Hc * Wc);
    const float* mk = mask + nc * MDd;      // wave-uniform -> scalar loads
    const float* wr = weight + nc * MDd;    // wave-uniform -> scalar loads
    const float  bi = bias[nc];

    // Build packed elements: high word = raw bits of key (mx value), low word
    // = raw bits of weight. mk[27+d] - v == (-v) + mk[27+d] bit-exactly.
    double key[MDd];
    #pragma unroll
    for (int c = 0; c < 3; ++c) {
        #pragma unroll
        for (int r = 0; r < 3; ++r) {
            #pragma unroll
            for (int s = 0; s < 3; ++s) {
                const int d = c * 9 + r * 3 + s;
                const float v = xb[(c * Hc + ho + r) * Wc + wo + s];
                const unsigned long long kp =
                    ((unsigned long long)__float_as_uint(v + mk[d]) << 32) |
                    __float_as_uint(wr[d]);
                const unsigned long long kn =
                    ((unsigned long long)__float_as_uint(mk[27 + d] - v) << 32) |
                    __float_as_uint(wr[27 + d]);
                key[d]      = __longlong_as_double((long long)kp);
                key[27 + d] = __longlong_as_double((long long)kn);
            }
        }
    }
    __builtin_amdgcn_sched_barrier(0);   // build may not bleed into the sort

    // Flattened sorting network. After full unroll every NET[ci] index is a
    // compile-time constant (array stays in registers).
    #pragma unroll
    for (int ci = 0; ci < NCE; ++ci) {
        ce(key[NET[ci].lo], key[NET[ci].hi]);
        if (ci % FENCE_EVERY == FENCE_EVERY - 1)
            __builtin_amdgcn_sched_barrier(0);
    }
    __builtin_amdgcn_sched_barrier(0);   // sort may not bleed into the cumsum

    // Sequential fp32 cumsum of the (exact, raw-bits) weights in sorted
    // descending-key order — bit-matches the reference summation. Track the
    // key of the last rank whose cumulative weight <= bias; default rank 0.
    const unsigned long long u0 =
        (unsigned long long)__double_as_longlong(key[0]);
    float acc = 0.0f;
    float sel = __uint_as_float((unsigned)(u0 >> 32));
    #pragma unroll
    for (int r = 0; r < MDd; ++r) {
        const unsigned long long u =
            (unsigned long long)__double_as_longlong(key[r]);
        acc += __uint_as_float((unsigned)u);            // low word: weight
        const float kv = __uint_as_float((unsigned)(u >> 32)); // high: key
        sel = (acc <= bi) ? kv : sel;
    }

    out[n * NCH + nc] = sel;
}

extern "C" void kernel_launch(void* const* d_in, const int* in_sizes, int n_in,
                              void* d_out, int out_size, void* d_ws, size_t ws_size,
                              hipStream_t stream) {
    const float* x      = (const float*)d_in[0];
    const float* weight = (const float*)d_in[1];
    const float* bias   = (const float*)d_in[2];
    const float* mask   = (const float*)d_in[3];
    float* out = (float*)d_out;

    const int ngrp = (Ntot + 63) / 64;      // 1561
    dim3 grid(ngrp * 2);                    // x2 blocks: 8 nc / 4 waves
    wos_kernel<<<grid, 256, 0, stream>>>(x, weight, bias, mask, out);
}